// Round 3
// baseline (1216.711 us; speedup 1.0000x reference)
//
#include <hip/hip_runtime.h>
#include <float.h>
#include <math.h>

#define NROWS 512
#define DIM 1024
#define NTRAIN 100000
#define MAXK 200
#define NCLS 1000
#define CAP 512        // finalize working set
#define CAP2 4096      // candidate list per row
#define BBCAP 3072
#define INV_T (1.0f/0.07f)
#define C0 8192        // exact-select prefix columns
#define NKS (DIM/32)   // 32 K-steps

typedef _Float16 f16x8 __attribute__((ext_vector_type(8)));
typedef _Float16 f16x4 __attribute__((ext_vector_type(4)));
typedef float f32x4 __attribute__((ext_vector_type(4)));

__device__ __forceinline__ unsigned fkey(float f) {
    unsigned u = __float_as_uint(f);
    return (u & 0x80000000u) ? ~u : (u | 0x80000000u);
}
__device__ __forceinline__ float inv_fkey(unsigned k) {
    return (k & 0x80000000u) ? __uint_as_float(k & 0x7fffffffu)
                             : __uint_as_float(~k);
}
__device__ __forceinline__ void gl_lds16(const void* g, void* l) {
    __builtin_amdgcn_global_load_lds(
        (const __attribute__((address_space(1))) unsigned int*)g,
        (__attribute__((address_space(3))) unsigned int*)l, 16, 0, 0);
}

// ---------------- fp32 -> f16 hi/lo split (A only; B fused into GEMM) ----------------
__global__ __launch_bounds__(256) void convert_split(
    const float* __restrict__ in, _Float16* __restrict__ hi,
    _Float16* __restrict__ lo, long long n)
{
    long long i0 = ((long long)blockIdx.x * 256 + threadIdx.x) * 4;
    long long stride = (long long)gridDim.x * 1024;
    for (long long i = i0; i < n; i += stride) {
        float4 v = *reinterpret_cast<const float4*>(&in[i]);
        float vv[4] = {v.x, v.y, v.z, v.w};
        f16x4 h, l;
        #pragma unroll
        for (int j = 0; j < 4; ++j) {
            _Float16 hh = (_Float16)vv[j];
            h[j] = hh;
            l[j] = (_Float16)(vv[j] - (float)hh);
        }
        *reinterpret_cast<f16x4*>(&hi[i]) = h;
        *reinterpret_cast<f16x4*>(&lo[i]) = l;
    }
}

// ---------------- fused GEMM: stage B fp32->f16hi/lo in-kernel ----------------
// 128x128 tile, BK=32, 4 waves (64x64 each), 3-term f16 split MFMA.
// LDS slot-major: [buf][hi/lo][slot(=k/8)][row][8 f16] -> conflict-free b128.
__global__ __launch_bounds__(256) void gemm_fused(
    const _Float16* __restrict__ Ahi, const _Float16* __restrict__ Alo,
    const float* __restrict__ B, float* __restrict__ sims, int sstride,
    int chunk_start, int cvalid, int materialize, const float* __restrict__ L,
    float* __restrict__ cv, int* __restrict__ ci, int* __restrict__ cc)
{
    __shared__ _Float16 sA[2][2][4][128][8];   // 32 KB
    __shared__ _Float16 sB[2][2][4][128][8];   // 32 KB
    const int tid = threadIdx.x;
    const int lane = tid & 63;
    const int wave = tid >> 6;

    // bijective XCD swizzle (gridDim.x % 8 == 0): 4 m-blocks of a B panel -> same XCD
    const int nwg = gridDim.x;
    const int wg = (blockIdx.x & 7) * (nwg >> 3) + (blockIdx.x >> 3);
    const int mt = wg & 3, nt = wg >> 2;       // m fastest: B panel reuse
    const int m0 = mt * 128, n0 = nt * 128;
    const int wm = wave >> 1, wn = wave & 1;

    // B staging ids: thread -> (row rB, half jB); 4 float4 loads per K-step
    const int rB = tid & 127, jB = tid >> 7;
    int rgB = chunk_start + n0 + rB;
    const int rmax = chunk_start + cvalid - 1;
    if (rgB > rmax) rgB = rmax;                 // clamp pad rows (filtered later)
    const float* Bsrc = B + (size_t)rgB * DIM + jB * 16;

    float4 bf[4];
    auto stageA = [&](int buf, int k0) {
        #pragma unroll
        for (int i = 0; i < 2; ++i) {
            int c = wave * 64 + i * 256 + lane;   // chunk = slot*128 + row
            int s = c >> 7, r = c & 127;
            size_t g = (size_t)(m0 + r) * DIM + (k0 + s * 8);
            char* dh = (char*)&sA[buf][0][0][0][0] + (wave * 64 + i * 256) * 16;
            char* dl = (char*)&sA[buf][1][0][0][0] + (wave * 64 + i * 256) * 16;
            gl_lds16(Ahi + g, dh);
            gl_lds16(Alo + g, dl);
        }
    };
    auto loadB = [&](int k0) {
        #pragma unroll
        for (int q = 0; q < 4; ++q)
            bf[q] = *reinterpret_cast<const float4*>(Bsrc + k0 + q * 4);
    };
    auto writeB = [&](int buf) {
        #pragma unroll
        for (int q = 0; q < 4; ++q) {
            float vv[4] = {bf[q].x, bf[q].y, bf[q].z, bf[q].w};
            f16x4 h, l;
            #pragma unroll
            for (int e = 0; e < 4; ++e) {
                _Float16 hh = (_Float16)vv[e];
                h[e] = hh;
                l[e] = (_Float16)(vv[e] - (float)hh);
            }
            int k = jB * 16 + q * 4;
            int s = k >> 3, half = (k >> 2) & 1;
            *reinterpret_cast<f16x4*>(&sB[buf][0][s][rB][half * 4]) = h;
            *reinterpret_cast<f16x4*>(&sB[buf][1][s][rB][half * 4]) = l;
        }
    };

    f32x4 acc[4][4] = {};

    // prologue: stage K-step 0 into buf 0
    stageA(0, 0);
    loadB(0);
    writeB(0);
    __syncthreads();

#define KSTEP(BUF, T)                                                          \
    {                                                                          \
        const int tn = (T) + 1;                                                \
        if (tn < NKS) { stageA((BUF) ^ 1, tn * 32); loadB(tn * 32); }          \
        f16x8 ah[4], al[4], bh[4], bl[4];                                      \
        _Pragma("unroll")                                                      \
        for (int m = 0; m < 4; ++m) {                                          \
            int rr = wm * 64 + m * 16 + (lane & 15);                           \
            ah[m] = *reinterpret_cast<const f16x8*>(&sA[BUF][0][lane >> 4][rr][0]); \
            al[m] = *reinterpret_cast<const f16x8*>(&sA[BUF][1][lane >> 4][rr][0]); \
        }                                                                      \
        _Pragma("unroll")                                                      \
        for (int n = 0; n < 4; ++n) {                                          \
            int rr = wn * 64 + n * 16 + (lane & 15);                           \
            bh[n] = *reinterpret_cast<const f16x8*>(&sB[BUF][0][lane >> 4][rr][0]); \
            bl[n] = *reinterpret_cast<const f16x8*>(&sB[BUF][1][lane >> 4][rr][0]); \
        }                                                                      \
        _Pragma("unroll")                                                      \
        for (int m = 0; m < 4; ++m)                                            \
            _Pragma("unroll")                                                  \
            for (int n = 0; n < 4; ++n) {                                      \
                acc[m][n] = __builtin_amdgcn_mfma_f32_16x16x32_f16(ah[m], bh[n], acc[m][n], 0, 0, 0); \
                acc[m][n] = __builtin_amdgcn_mfma_f32_16x16x32_f16(ah[m], bl[n], acc[m][n], 0, 0, 0); \
                acc[m][n] = __builtin_amdgcn_mfma_f32_16x16x32_f16(al[m], bh[n], acc[m][n], 0, 0, 0); \
            }                                                                  \
        if (tn < NKS) writeB((BUF) ^ 1);                                       \
        __syncthreads();                                                       \
    }

    for (int t = 0; t < NKS; t += 2) { KSTEP(0, t) KSTEP(1, t + 1) }
#undef KSTEP

    // epilogue: C/D layout col=lane&15, row=(lane>>4)*4+reg
    const int q4 = (lane >> 4) * 4;
    const int cL = lane & 15;
    if (materialize) {
        #pragma unroll
        for (int m = 0; m < 4; ++m)
            #pragma unroll
            for (int j = 0; j < 4; ++j) {
                int orow = m0 + wm * 64 + m * 16 + q4 + j;
                float* dst = sims + (size_t)orow * sstride + n0 + wn * 64 + cL;
                #pragma unroll
                for (int n = 0; n < 4; ++n)
                    dst[n * 16] = acc[m][n][j];
            }
    } else {
        #pragma unroll
        for (int m = 0; m < 4; ++m)
            #pragma unroll
            for (int j = 0; j < 4; ++j) {
                int orow = m0 + wm * 64 + m * 16 + q4 + j;
                float Lr = L[orow];
                #pragma unroll
                for (int n = 0; n < 4; ++n) {
                    float v = acc[m][n][j];
                    int ocol = n0 + wn * 64 + n * 16 + cL;
                    if (ocol < cvalid && v >= Lr) {
                        int p = atomicAdd(&cc[orow], 1);
                        if (p < CAP2) {
                            cv[(size_t)orow * CAP2 + p] = v;
                            ci[(size_t)orow * CAP2 + p] = chunk_start + ocol;
                        }
                    }
                }
            }
    }
}

// ---------------- exact radix select on first C0 cols; seeds candidates + threshold L ----------------
__global__ __launch_bounds__(256) void select0(
    const float* __restrict__ sims, float* __restrict__ cv, int* __restrict__ ci,
    int* __restrict__ cc, float* __restrict__ L)
{
    __shared__ int hist[2048];
    __shared__ float bbv[BBCAP];
    __shared__ int bbi[BBCAP];
    __shared__ int s_binB, s_above, s_ccnt, s_bcnt, s_binB2;
    const int tid = threadIdx.x;
    const int r = blockIdx.x;
    const float* srow = sims + (size_t)r * C0;

    for (int i = tid; i < 2048; i += 256) hist[i] = 0;
    if (tid == 0) { s_ccnt = 0; s_bcnt = 0; }
    __syncthreads();

    for (int i = tid; i < C0; i += 256)
        atomicAdd(&hist[fkey(srow[i]) >> 21], 1);
    __syncthreads();
    if (tid == 0) {
        int cum = 0, b = 2047;
        for (; b > 0; --b) { if (cum + hist[b] >= MAXK) break; cum += hist[b]; }
        s_binB = b; s_above = cum;
    }
    __syncthreads();
    const int binB = s_binB;

    for (int i = tid; i < C0; i += 256) {
        float v = srow[i];
        int b = (int)(fkey(v) >> 21);
        if (b > binB) {
            int p = atomicAdd(&s_ccnt, 1);
            if (p < CAP2) { cv[(size_t)r * CAP2 + p] = v; ci[(size_t)r * CAP2 + p] = i; }
        } else if (b == binB) {
            int p = atomicAdd(&s_bcnt, 1);
            if (p < BBCAP) { bbv[p] = v; bbi[p] = i; }
        }
    }
    __syncthreads();
    const int bcnt = min(s_bcnt, BBCAP);
    const int need = MAXK - s_above;

    for (int i = tid; i < 2048; i += 256) hist[i] = 0;
    __syncthreads();
    for (int i = tid; i < bcnt; i += 256)
        atomicAdd(&hist[(fkey(bbv[i]) >> 10) & 0x7FF], 1);
    __syncthreads();
    if (tid == 0) {
        int cum = 0, b = 2047;
        for (; b > 0; --b) { if (cum + hist[b] >= need) break; cum += hist[b]; }
        s_binB2 = b;
    }
    __syncthreads();
    const int binB2 = s_binB2;
    for (int i = tid; i < bcnt; i += 256) {
        int sub = (int)((fkey(bbv[i]) >> 10) & 0x7FF);
        if (sub >= binB2) {
            int p = atomicAdd(&s_ccnt, 1);
            if (p < CAP2) { cv[(size_t)r * CAP2 + p] = bbv[i]; ci[(size_t)r * CAP2 + p] = bbi[i]; }
        }
    }
    __syncthreads();
    if (tid == 0) {
        cc[r] = min(s_ccnt, CAP2);
        unsigned edge = ((unsigned)binB << 21) | ((unsigned)binB2 << 10);
        L[r] = inv_fkey(edge);   // all kept values >= L; filter keeps v >= L
    }
}

// ---------------- final: radix-select top-200 superset from candidates, sort, softmax, scatter ----------------
__global__ __launch_bounds__(256) void finalize2(
    const float* __restrict__ cv, const int* __restrict__ ci, const int* __restrict__ cc,
    const int* __restrict__ labels, float* __restrict__ out)
{
    __shared__ int hist[2048];
    __shared__ float sval[CAP];
    __shared__ int   sidx[CAP];
    __shared__ float bbv[BBCAP];
    __shared__ int   bbi[BBCAP];
    __shared__ float cls[NCLS];
    __shared__ float s_sum;
    __shared__ int s_binB, s_above, s_cnt, s_bcnt, s_binB2;
    const int tid = threadIdx.x;
    const int r = blockIdx.x;
    const int M = min(cc[r], CAP2);
    const float* cvr = cv + (size_t)r * CAP2;
    const int*   cir = ci + (size_t)r * CAP2;

    for (int i = tid; i < 2048; i += 256) hist[i] = 0;
    if (tid == 0) { s_cnt = 0; s_bcnt = 0; }
    __syncthreads();
    for (int i = tid; i < M; i += 256)
        atomicAdd(&hist[fkey(cvr[i]) >> 21], 1);
    __syncthreads();
    if (tid == 0) {
        int cum = 0, b = 2047;
        for (; b > 0; --b) { if (cum + hist[b] >= MAXK) break; cum += hist[b]; }
        s_binB = b; s_above = cum;
    }
    __syncthreads();
    const int binB = s_binB;

    for (int i = tid; i < M; i += 256) {
        float v = cvr[i];
        int b = (int)(fkey(v) >> 21);
        if (b > binB) {
            int p = atomicAdd(&s_cnt, 1);
            if (p < CAP) { sval[p] = v; sidx[p] = cir[i]; }
        } else if (b == binB) {
            int p = atomicAdd(&s_bcnt, 1);
            if (p < BBCAP) { bbv[p] = v; bbi[p] = cir[i]; }
        }
    }
    __syncthreads();
    const int bcnt = min(s_bcnt, BBCAP);
    const int need = MAXK - s_above;
    for (int i = tid; i < 2048; i += 256) hist[i] = 0;
    __syncthreads();
    for (int i = tid; i < bcnt; i += 256)
        atomicAdd(&hist[(fkey(bbv[i]) >> 10) & 0x7FF], 1);
    __syncthreads();
    if (tid == 0) {
        int cum = 0, b = 2047;
        for (; b > 0; --b) { if (cum + hist[b] >= need) break; cum += hist[b]; }
        s_binB2 = b;
    }
    __syncthreads();
    const int binB2 = s_binB2;
    for (int i = tid; i < bcnt; i += 256) {
        int sub = (int)((fkey(bbv[i]) >> 10) & 0x7FF);
        if (sub >= binB2) {
            int p = atomicAdd(&s_cnt, 1);
            if (p < CAP) { sval[p] = bbv[i]; sidx[p] = bbi[i]; }
        }
    }
    __syncthreads();
    const int kept = min(s_cnt, CAP);
    for (int i = kept + tid; i < CAP; i += 256) { sval[i] = -FLT_MAX; sidx[i] = 0x7FFFFFFF; }
    __syncthreads();

    // bitonic sort, descending by (val desc, idx asc)
    for (int k = 2; k <= CAP; k <<= 1)
        for (int j = k >> 1; j > 0; j >>= 1) {
            for (int i = tid; i < CAP; i += 256) {
                int l = i ^ j;
                if (l > i) {
                    float av = sval[i], bv2 = sval[l];
                    int ai = sidx[i], bi = sidx[l];
                    bool iGTl = (av > bv2) || (av == bv2 && ai < bi);
                    bool sw = ((i & k) == 0) ? (!iGTl) : iGTl;
                    if (sw) { sval[i] = bv2; sval[l] = av; sidx[i] = bi; sidx[l] = ai; }
                }
            }
            __syncthreads();
        }

    float mx = sval[0];
    if (tid == 0) s_sum = 0.f;
    __syncthreads();
    float part = 0.f;
    for (int i = tid; i < MAXK; i += 256) {
        float e = expf((sval[i] - mx) * INV_T);
        sval[i] = e;
        part += e;
    }
    atomicAdd(&s_sum, part);
    __syncthreads();
    float inv = 1.f / s_sum;
    for (int i = tid; i < MAXK; i += 256) {
        sval[i] *= inv;
        sidx[i] = labels[sidx[i]];
    }
    for (int c = tid; c < NCLS; c += 256) cls[c] = 0.f;
    __syncthreads();

    const int KS[4] = {10, 20, 100, 200};
    int prev = 0;
    for (int s = 0; s < 4; ++s) {
        for (int i = prev + tid; i < KS[s]; i += 256)
            atomicAdd(&cls[sidx[i]], sval[i]);
        __syncthreads();
        float* o = out + ((size_t)s * NROWS + r) * NCLS;
        for (int c = tid; c < NCLS; c += 256) o[c] = cls[c];
        __syncthreads();
        prev = KS[s];
    }
}

// ---------------- host launcher ----------------
extern "C" void kernel_launch(void* const* d_in, const int* in_sizes, int n_in,
                              void* d_out, int out_size, void* d_ws, size_t ws_size,
                              hipStream_t stream)
{
    const float* A = (const float*)d_in[0];       // [512,1024]
    const float* B = (const float*)d_in[1];       // [100000,1024]
    const int* labels = (const int*)d_in[2];      // [100000]
    float* out = (float*)d_out;                   // [4,512,1000] f32

    char* ws = (char*)d_ws;
    size_t off = 0;
    auto carve = [&](size_t bytes) -> void* {
        void* p = ws + off;
        off = (off + bytes + 255) & ~(size_t)255;
        return p;
    };
    _Float16* Ahi = (_Float16*)carve((size_t)NROWS * DIM * 2);
    _Float16* Alo = (_Float16*)carve((size_t)NROWS * DIM * 2);
    float* cv = (float*)carve((size_t)NROWS * CAP2 * 4);
    int*   ci = (int*)carve((size_t)NROWS * CAP2 * 4);
    int*   cc = (int*)carve((size_t)NROWS * 4);
    float* L  = (float*)carve((size_t)NROWS * 4);
    float* sims = (float*)carve((size_t)NROWS * C0 * 4);

    // A split (1 MB out each)
    convert_split<<<512, 256, 0, stream>>>(A, Ahi, Alo, (long long)NROWS * DIM);

    // exact prefix: materialize sims for first C0 cols, radix-select, set threshold L
    gemm_fused<<<4 * (C0 / 128), 256, 0, stream>>>(Ahi, Alo, B, sims, C0,
        0, C0, 1, L, cv, ci, cc);
    select0<<<NROWS, 256, 0, stream>>>(sims, cv, ci, cc, L);

    // single filtered pass over remaining columns
    int cval = NTRAIN - C0;                       // 91808
    int nt2 = (cval + 127) / 128;                 // 718 -> grid 2872 (div by 8)
    gemm_fused<<<4 * nt2, 256, 0, stream>>>(Ahi, Alo, B, nullptr, 0,
        C0, cval, 0, L, cv, ci, cc);

    finalize2<<<NROWS, 256, 0, stream>>>(cv, ci, cc, labels, out);
}